// Round 1
// baseline (795.140 us; speedup 1.0000x reference)
//
#include <hip/hip_runtime.h>
#include <stdint.h>

// SelfOrganizingBrain: B=1024, IN=784, E=256, NCLS=10, BRAIN=4, ADIM=3, N=64, NJUMPS=4
// Key structural facts exploited:
//  - gumbel-softmax-hard forward value == hard one-hot -> address = argmax(logits + gumbel)
//  - flatten_onehot + einsum('bn,bne->be') selects exactly ONE block per row
//    -> dense 86 GFLOP collapses to ~2.6 GFLOP of per-row routed matvecs.
//  - gumbel noise must be bit-exact JAX threefry2x32 (noise >> logits).

#define BATCH   1024
#define INDIM   784
#define EDIM    256
#define NBLK    64
#define CHUNK   8     // rows per block-eval workgroup chunk
#define ROWS    8     // rows per WG in row-parallel kernels
#define HPAD    12    // LDS H stride in words (multiple of 4 -> b128-aligned; breaks pow2 conflicts)
#define GRID_BE 192   // max chunks = 64 + floor((1024-64)/8) = 184 <= 192

// ---------------- threefry2x32 (exact JAX semantics) ----------------
__host__ __device__ inline uint32_t rotl32(uint32_t x, uint32_t d) {
  return (x << d) | (x >> (32u - d));
}

__host__ __device__ inline void threefry2x32(uint32_t k0, uint32_t k1,
                                             uint32_t x0, uint32_t x1,
                                             uint32_t* o0, uint32_t* o1) {
  uint32_t ks2 = k0 ^ k1 ^ 0x1BD11BDAu;
  x0 += k0; x1 += k1;
#define TF_R(a) { x0 += x1; x1 = rotl32(x1, a); x1 ^= x0; }
  TF_R(13) TF_R(15) TF_R(26) TF_R(6)   x0 += k1;  x1 += ks2 + 1u;
  TF_R(17) TF_R(29) TF_R(16) TF_R(24)  x0 += ks2; x1 += k0  + 2u;
  TF_R(13) TF_R(15) TF_R(26) TF_R(6)   x0 += k0;  x1 += k1  + 3u;
  TF_R(17) TF_R(29) TF_R(16) TF_R(24)  x0 += k1;  x1 += ks2 + 4u;
  TF_R(13) TF_R(15) TF_R(26) TF_R(6)   x0 += ks2; x1 += k0  + 5u;
#undef TF_R
  *o0 = x0; *o1 = x1;
}

// JAX random_bits for count=12288 (B*ADIM*BRAIN): iota split in half, pairwise threefry.
__device__ inline uint32_t jax_bits12288(uint32_t k0, uint32_t k1, uint32_t L) {
  uint32_t o0, o1;
  if (L < 6144u) { threefry2x32(k0, k1, L, L + 6144u, &o0, &o1); return o0; }
  else           { threefry2x32(k0, k1, L - 6144u, L, &o0, &o1); return o1; }
}

__device__ inline float jax_uniform(uint32_t bits) {
  const float minv = 1e-6f;
  const float maxv = (float)(1.0 - 1e-06);   // match JAX f32 conversion of python double
  const float span = maxv - minv;            // f32, compile-time
  uint32_t fb = (bits >> 9) | 0x3f800000u;
  float f = __uint_as_float(fb) - 1.0f;
  float u = __fadd_rn(__fmul_rn(f, span), minv);  // forbid fma contraction (match XLA mul+add)
  return fmaxf(minv, u);
}

// ---------------- embed: state = x @ W_emb + b_emb ----------------
__global__ __launch_bounds__(256) void k_embed(
    const float* __restrict__ x, const float* __restrict__ Wemb,
    const float* __restrict__ bemb,
    float* __restrict__ stateA, float* __restrict__ initial,
    int* __restrict__ counters0) {
  const int wg = blockIdx.x, j = threadIdx.x;
  if (wg == 0 && j < 160) counters0[j] = 0;   // zero counter set 0 for addr step 0
  const int b0 = wg * ROWS;
  float acc[ROWS];
#pragma unroll
  for (int i = 0; i < ROWS; i++) acc[i] = 0.f;
#pragma unroll 4
  for (int k = 0; k < INDIM; k++) {
    float w = Wemb[k * EDIM + j];
#pragma unroll
    for (int i = 0; i < ROWS; i++)
      acc[i] = fmaf(x[(b0 + i) * INDIM + k], w, acc[i]);  // uniform addr -> scalar loads
  }
  float bb = bemb[j];
#pragma unroll
  for (int i = 0; i < ROWS; i++) {
    float v = acc[i] + bb;
    stateA[(b0 + i) * EDIM + j] = v;
    initial[(b0 + i) * EDIM + j] = v;
  }
}

// ---------------- address MLP + gumbel argmax + routing bookkeeping ----------------
// step 0: init n_cur/exited for all rows, count all.
// step 1..3: for non-exited rows: n_new; n_new==0 -> exit (n_next=-1) else route (count).
// step 4: n_next = final block (exited -> 0), count all rows.
__global__ __launch_bounds__(256) void k_addr(
    const float* __restrict__ state,
    const float* __restrict__ aW1, const float* __restrict__ ab1,
    const float* __restrict__ aW2, const float* __restrict__ ab2,
    int* __restrict__ n_cur, int* __restrict__ exited, int* __restrict__ n_next,
    int* __restrict__ count, int step, uint32_t fk0, uint32_t fk1) {
  __shared__ float Hlds[EDIM][HPAD];   // [k][row]
  __shared__ float vals[ROWS][12];
  const int wg = blockIdx.x, j = threadIdx.x;
  const int b0 = wg * ROWS;

  float acc[ROWS];
#pragma unroll
  for (int i = 0; i < ROWS; i++) acc[i] = 0.f;
#pragma unroll 4
  for (int k = 0; k < EDIM; k++) {
    float w = aW1[k * EDIM + j];
#pragma unroll
    for (int i = 0; i < ROWS; i++)
      acc[i] = fmaf(state[(b0 + i) * EDIM + k], w, acc[i]);
  }
  float bb = ab1[j];
#pragma unroll
  for (int i = 0; i < ROWS; i++) Hlds[j][i] = fmaxf(acc[i] + bb, 0.f);
  __syncthreads();

  if (j < 96) {                        // (row i, logit c) pairs: 8*12
    int i = j / 12, c = j % 12;
    float a2 = 0.f;
#pragma unroll 4
    for (int k = 0; k < EDIM; k++) a2 = fmaf(Hlds[k][i], aW2[k * 12 + c], a2);
    float logit = a2 + ab2[c];
    uint32_t L = (uint32_t)((b0 + i) * 12 + c);
    float u = jax_uniform(jax_bits12288(fk0, fk1, L));
    float g = -logf(-logf(u));
    vals[i][c] = logit + g;            // TAU=1; softmax is monotone -> argmax on this
  }
  __syncthreads();

  if (j < ROWS) {
    const int b = b0 + j;
    int idx0 = 0, idx1 = 0, idx2 = 0;
    {
      float best = vals[j][0];
#pragma unroll
      for (int c = 1; c < 4; c++) { float v = vals[j][c];     if (v > best) { best = v; idx0 = c; } }
    }
    {
      float best = vals[j][4];
#pragma unroll
      for (int c = 1; c < 4; c++) { float v = vals[j][4 + c]; if (v > best) { best = v; idx1 = c; } }
    }
    {
      float best = vals[j][8];
#pragma unroll
      for (int c = 1; c < 4; c++) { float v = vals[j][8 + c]; if (v > best) { best = v; idx2 = c; } }
    }
    int nn = idx0 * 16 + idx1 * 4 + idx2;
    int nxt;
    if (step == 0) {
      exited[b] = 0; n_cur[b] = nn; nxt = nn;
    } else if (step < 4) {
      if (exited[b])      nxt = -1;                      // frozen: copy-forward
      else if (nn == 0) { exited[b] = 1; nxt = -1; }     // exits now; state frozen
      else              { n_cur[b] = nn; nxt = nn; }
    } else {
      nxt = exited[b] ? 0 : nn;                          // final block (origin for exited)
    }
    n_next[b] = nxt;
    if (nxt >= 0) atomicAdd(&count[nxt], 1);
  }
}

// ---------------- scatter rows into per-block contiguous lists ----------------
__global__ __launch_bounds__(256) void k_scatter(
    const int* __restrict__ n_next, const int* __restrict__ count,
    int* __restrict__ cursor, int* __restrict__ ncopy,
    int* __restrict__ list, int* __restrict__ copylist) {
  __shared__ int offs[NBLK];
  const int j = threadIdx.x;
  if (j < 64) {
    int cnt = count[j];
    int inc = cnt;
#pragma unroll
    for (int d = 1; d < 64; d <<= 1) { int t = __shfl_up(inc, d); if (j >= d) inc += t; }
    offs[j] = inc - cnt;               // exclusive prefix
  }
  __syncthreads();
  const int b = blockIdx.x * 256 + j;
  int nn = n_next[b];
  if (nn >= 0) {
    int pos = atomicAdd(&cursor[nn], 1);
    list[offs[nn] + pos] = b;
  } else {
    int pos = atomicAdd(ncopy, 1);
    copylist[pos] = b;
  }
}

// ---------------- routed block eval: out = relu(relu(S@W1+b1)@W2+b2)/(||S||+1e-6) ----------------
__global__ __launch_bounds__(256) void k_blocks(
    const float* __restrict__ sin,
    const float* __restrict__ W1, const float* __restrict__ b1,
    const float* __restrict__ W2, const float* __restrict__ b2,
    const int* __restrict__ count, const int* __restrict__ ncopy,
    const int* __restrict__ list, const int* __restrict__ copylist,
    const float* __restrict__ initial, float* __restrict__ sout,
    int* __restrict__ counters_next, int is_final) {
  __shared__ float Hlds[EDIM][HPAD];
  __shared__ int   meta[4];            // n, start, m, total_chunks
  __shared__ float wsum[4][CHUNK];
  __shared__ float denom[CHUNK];
  const int j = threadIdx.x, c = blockIdx.x;

  if (c == 0 && j < 160) counters_next[j] = 0;   // zero NEXT round's counter set (no race)

  if (j < 64) {                        // wave 0 resolves this WG's chunk from counts
    int cnt = count[j];
    int nch = (cnt + CHUNK - 1) / CHUNK;
    int icnt = cnt, inch = nch;
#pragma unroll
    for (int d = 1; d < 64; d <<= 1) {
      int t1 = __shfl_up(icnt, d), t2 = __shfl_up(inch, d);
      if (j >= d) { icnt += t1; inch += t2; }
    }
    int ecnt = icnt - cnt, ench = inch - nch;
    int total = __shfl(inch, 63);
    if (j == 0) meta[3] = total;
    if (c >= ench && c < ench + nch) {
      int local = c - ench;
      meta[0] = j;
      meta[1] = ecnt + local * CHUNK;
      meta[2] = min(CHUNK, cnt - local * CHUNK);
    }
  }
  __syncthreads();
  const int total_nch = meta[3];

  if (c >= total_nch) {                // spare WGs copy frozen (exited) rows forward
    int nc = *ncopy;
    for (int r = c - total_nch; r < nc; r += gridDim.x - total_nch) {
      int row = copylist[r];
      sout[row * EDIM + j] = sin[row * EDIM + j];
    }
    return;
  }
  const int n = meta[0], start = meta[1], m = meta[2];

  int rows[CHUNK];
#pragma unroll
  for (int i = 0; i < CHUNK; i++) rows[i] = list[start + min(i, m - 1)];

  // norms of input rows (parallel over 256 threads, butterfly within wave)
  float sq[CHUNK];
#pragma unroll
  for (int i = 0; i < CHUNK; i++) { float v = sin[rows[i] * EDIM + j]; sq[i] = v * v; }
#pragma unroll
  for (int d = 32; d >= 1; d >>= 1) {
#pragma unroll
    for (int i = 0; i < CHUNK; i++) sq[i] += __shfl_xor(sq[i], d);
  }
  if ((j & 63) == 0) {
#pragma unroll
    for (int i = 0; i < CHUNK; i++) wsum[j >> 6][i] = sq[i];
  }
  __syncthreads();
  if (j < CHUNK) {
    float s = wsum[0][j] + wsum[1][j] + wsum[2][j] + wsum[3][j];
    denom[j] = sqrtf(s) + 1e-6f;
  }
  __syncthreads();

  // layer 1
  const float* W1n = W1 + (size_t)n * EDIM * EDIM;
  float acc[CHUNK];
#pragma unroll
  for (int i = 0; i < CHUNK; i++) acc[i] = 0.f;
#pragma unroll 4
  for (int k = 0; k < EDIM; k++) {
    float w = W1n[k * EDIM + j];
#pragma unroll
    for (int i = 0; i < CHUNK; i++)
      acc[i] = fmaf(sin[rows[i] * EDIM + k], w, acc[i]);   // uniform addr -> scalar loads
  }
  float bb1 = b1[n * EDIM + j];
#pragma unroll
  for (int i = 0; i < CHUNK; i++) Hlds[j][i] = fmaxf(acc[i] + bb1, 0.f);
  __syncthreads();

  // layer 2 (H via 2x ds_read_b128 broadcast per k)
  const float* W2n = W2 + (size_t)n * EDIM * EDIM;
  float acc2[CHUNK];
#pragma unroll
  for (int i = 0; i < CHUNK; i++) acc2[i] = 0.f;
#pragma unroll 2
  for (int k = 0; k < EDIM; k++) {
    float w = W2n[k * EDIM + j];
#pragma unroll
    for (int i = 0; i < CHUNK; i++) acc2[i] = fmaf(Hlds[k][i], w, acc2[i]);
  }
  float bb2 = b2[n * EDIM + j];
#pragma unroll
  for (int i = 0; i < CHUNK; i++) {
    if (i < m) {
      float v = fmaxf(acc2[i] + bb2, 0.f) / denom[i];
      int row = rows[i];
      if (is_final) sout[row * EDIM + j] = v + initial[row * EDIM + j];
      else          sout[row * EDIM + j] = v;
    }
  }
}

// ---------------- output head: relu(final@oW1+ob1)@oW2+ob2 ----------------
__global__ __launch_bounds__(256) void k_head(
    const float* __restrict__ fin,
    const float* __restrict__ oW1, const float* __restrict__ ob1,
    const float* __restrict__ oW2, const float* __restrict__ ob2,
    float* __restrict__ out) {
  __shared__ float Hlds[EDIM][HPAD];
  const int wg = blockIdx.x, j = threadIdx.x;
  const int b0 = wg * ROWS;
  float acc[ROWS];
#pragma unroll
  for (int i = 0; i < ROWS; i++) acc[i] = 0.f;
#pragma unroll 4
  for (int k = 0; k < EDIM; k++) {
    float w = oW1[k * EDIM + j];
#pragma unroll
    for (int i = 0; i < ROWS; i++)
      acc[i] = fmaf(fin[(b0 + i) * EDIM + k], w, acc[i]);
  }
  float bb = ob1[j];
#pragma unroll
  for (int i = 0; i < ROWS; i++) Hlds[j][i] = fmaxf(acc[i] + bb, 0.f);
  __syncthreads();
  if (j < 80) {                        // (row i, class c): 8*10
    int i = j / 10, cc = j % 10;
    float a = 0.f;
#pragma unroll 4
    for (int k = 0; k < EDIM; k++) a = fmaf(Hlds[k][i], oW2[k * 10 + cc], a);
    out[(b0 + i) * 10 + cc] = a + ob2[cc];
  }
}

// ---------------- launch ----------------
extern "C" void kernel_launch(void* const* d_in, const int* in_sizes, int n_in,
                              void* d_out, int out_size, void* d_ws, size_t ws_size,
                              hipStream_t stream) {
  const float* x    = (const float*)d_in[0];
  const float* Wemb = (const float*)d_in[1];
  const float* bemb = (const float*)d_in[2];
  const float* stW1 = (const float*)d_in[3];
  const float* stb1 = (const float*)d_in[4];
  const float* stW2 = (const float*)d_in[5];
  const float* stb2 = (const float*)d_in[6];
  const float* aW1  = (const float*)d_in[7];
  const float* ab1  = (const float*)d_in[8];
  const float* aW2  = (const float*)d_in[9];
  const float* ab2  = (const float*)d_in[10];
  const float* oW1  = (const float*)d_in[11];
  const float* ob1  = (const float*)d_in[12];
  const float* oW2  = (const float*)d_in[13];
  const float* ob2  = (const float*)d_in[14];
  float* out = (float*)d_out;

  char* ws = (char*)d_ws;
  auto alloc = [&](size_t bytes) { char* p = ws; ws += (bytes + 255) & ~(size_t)255; return p; };
  float* stateA  = (float*)alloc((size_t)BATCH * EDIM * 4);
  float* stateB  = (float*)alloc((size_t)BATCH * EDIM * 4);
  float* initial = (float*)alloc((size_t)BATCH * EDIM * 4);
  float* finalb  = (float*)alloc((size_t)BATCH * EDIM * 4);
  int* n_cur  = (int*)alloc(BATCH * 4);
  int* exited = (int*)alloc(BATCH * 4);
  int* n_next = (int*)alloc(BATCH * 4);
  int* counters[2];
  counters[0] = (int*)alloc(160 * 4);   // [0:64) count, [64:128) cursor, [128] ncopy
  counters[1] = (int*)alloc(160 * 4);
  int* list     = (int*)alloc((BATCH + CHUNK) * 4);
  int* copylist = (int*)alloc((BATCH + CHUNK) * 4);

  // fold_in(key(42), s) on host: threefry(k=[0,42], x=[0,s])
  uint32_t fk0[5], fk1[5];
  for (uint32_t s = 0; s < 5; s++) threefry2x32(0u, 42u, 0u, s, &fk0[s], &fk1[s]);

  k_embed<<<BATCH / ROWS, 256, 0, stream>>>(x, Wemb, bemb, stateA, initial, counters[0]);

  float* cur = stateA;
  float* nxt = stateB;
  for (int j = 0; j < 5; j++) {
    int* cnt  = counters[j & 1];
    int* cntN = counters[(j + 1) & 1];
    k_addr<<<BATCH / ROWS, 256, 0, stream>>>(cur, aW1, ab1, aW2, ab2,
        n_cur, exited, n_next, cnt, j, fk0[j], fk1[j]);
    k_scatter<<<BATCH / 256, 256, 0, stream>>>(n_next, cnt, cnt + 64, cnt + 128,
        list, copylist);
    if (j < 4) {
      k_blocks<<<GRID_BE, 256, 0, stream>>>(cur, stW1, stb1, stW2, stb2,
          cnt, cnt + 128, list, copylist, (const float*)nullptr, nxt, cntN, 0);
      float* t = cur; cur = nxt; nxt = t;
    } else {
      k_blocks<<<GRID_BE, 256, 0, stream>>>(cur, stW1, stb1, stW2, stb2,
          cnt, cnt + 128, list, copylist, initial, finalb, cntN, 1);
    }
  }
  k_head<<<BATCH / ROWS, 256, 0, stream>>>(finalb, oW1, ob1, oW2, ob2, out);
}

// Round 2
// 419.189 us; speedup vs baseline: 1.8969x; 1.8969x over previous
//
#include <hip/hip_runtime.h>
#include <stdint.h>

// SelfOrganizingBrain: B=1024, IN=784, E=256, NCLS=10, N=64 blocks, NJUMPS=4.
// R1: K-split WG=1024 kernels (16 waves/WG) to fix 5% occupancy; k_scatter
// removed (ballot-scan of n_next inside k_blocks; frozen-copy inside k_addr).
// 12 dispatches: embed + 5x(addr, blocks) + head. All fp32 (argmax-critical).

#define BATCH 1024
#define EDIM  256
#define INDIM 784
#define GRID_BE 304   // max sum ceil(cnt_n/4) = 256 + 63*3/4 -> 304 (tight bound)

// ---------------- threefry2x32 (exact JAX semantics, validated R0) ----------------
__host__ __device__ inline uint32_t rotl32(uint32_t x, uint32_t d) {
  return (x << d) | (x >> (32u - d));
}
__host__ __device__ inline void threefry2x32(uint32_t k0, uint32_t k1,
                                             uint32_t x0, uint32_t x1,
                                             uint32_t* o0, uint32_t* o1) {
  uint32_t ks2 = k0 ^ k1 ^ 0x1BD11BDAu;
  x0 += k0; x1 += k1;
#define TF_R(a) { x0 += x1; x1 = rotl32(x1, a); x1 ^= x0; }
  TF_R(13) TF_R(15) TF_R(26) TF_R(6)   x0 += k1;  x1 += ks2 + 1u;
  TF_R(17) TF_R(29) TF_R(16) TF_R(24)  x0 += ks2; x1 += k0  + 2u;
  TF_R(13) TF_R(15) TF_R(26) TF_R(6)   x0 += k0;  x1 += k1  + 3u;
  TF_R(17) TF_R(29) TF_R(16) TF_R(24)  x0 += k1;  x1 += ks2 + 4u;
  TF_R(13) TF_R(15) TF_R(26) TF_R(6)   x0 += ks2; x1 += k0  + 5u;
#undef TF_R
  *o0 = x0; *o1 = x1;
}
__device__ inline uint32_t jax_bits12288(uint32_t k0, uint32_t k1, uint32_t L) {
  uint32_t o0, o1;
  if (L < 6144u) { threefry2x32(k0, k1, L, L + 6144u, &o0, &o1); return o0; }
  else           { threefry2x32(k0, k1, L - 6144u, L, &o0, &o1); return o1; }
}
__device__ inline float jax_uniform(uint32_t bits) {
  const float minv = 1e-6f;
  const float maxv = (float)(1.0 - 1e-06);
  const float span = maxv - minv;
  uint32_t fb = (bits >> 9) | 0x3f800000u;
  float f = __uint_as_float(fb) - 1.0f;
  float u = __fadd_rn(__fmul_rn(f, span), minv);
  return fmaxf(minv, u);
}

// ---------------- embed: state = x @ W_emb + b_emb  (8 rows/WG, 4 K-slices) ----------------
__global__ __launch_bounds__(1024) void k_embed(
    const float* __restrict__ x, const float* __restrict__ Wemb,
    const float* __restrict__ bemb,
    float* __restrict__ stateA, float* __restrict__ initial,
    int* __restrict__ count0) {
  __shared__ float P[4][256][8];   // 32KB partials [ks][col][row]
  const int t = threadIdx.x, wg = blockIdx.x;
  if (wg == 0 && t < 64) count0[t] = 0;
  const int j = t & 255, ks = t >> 8;
  const int b0 = wg * 8;
  float a[8] = {0.f,0.f,0.f,0.f,0.f,0.f,0.f,0.f};
  const float* xb = x + (size_t)b0 * INDIM;
  const int kb = ks * 196;              // 784/4, multiple of 4
#pragma unroll 2
  for (int k = kb; k < kb + 196; k += 4) {
    const float w0 = Wemb[(k+0)*EDIM + j], w1 = Wemb[(k+1)*EDIM + j],
                w2 = Wemb[(k+2)*EDIM + j], w3 = Wemb[(k+3)*EDIM + j];
#pragma unroll
    for (int i = 0; i < 8; i++) {
      const float4 s4 = *(const float4*)(xb + i * INDIM + k);  // same-addr L1 broadcast
      a[i] = fmaf(s4.x, w0, a[i]); a[i] = fmaf(s4.y, w1, a[i]);
      a[i] = fmaf(s4.z, w2, a[i]); a[i] = fmaf(s4.w, w3, a[i]);
    }
  }
  float4* pp = (float4*)&P[ks][j][0];
  pp[0] = make_float4(a[0], a[1], a[2], a[3]);
  pp[1] = make_float4(a[4], a[5], a[6], a[7]);
  __syncthreads();
  {
    const int j2 = t & 255, ih = t >> 8;
    const float bb = bemb[j2];
#pragma unroll
    for (int q = 0; q < 2; q++) {
      const int i = ih + q * 4;
      float s = P[0][j2][i] + P[1][j2][i] + P[2][j2][i] + P[3][j2][i] + bb;
      stateA[(size_t)(b0 + i) * EDIM + j2] = s;
      initial[(size_t)(b0 + i) * EDIM + j2] = s;
    }
  }
}

// ---------------- addr MLP + gumbel argmax + bookkeeping + frozen-copy ----------------
// 4 rows/WG, grid 256. Layer1: (col j, 4 K-slices of 64). Layer2: (c,i,ksl)=16x4x16.
__global__ __launch_bounds__(1024) void k_addr(
    const float* __restrict__ state,
    const float* __restrict__ aW1, const float* __restrict__ ab1,
    const float* __restrict__ aW2, const float* __restrict__ ab2,
    int* __restrict__ exited, int* __restrict__ n_next, int* __restrict__ count,
    float* __restrict__ sout, int step, uint32_t fk0, uint32_t fk1) {
  __shared__ float P[4][256][4];    // 16KB [ks][col][row]
  __shared__ float H[256][4];       // 4KB  [k][row]
  __shared__ float P2[16][4][16];   // 4KB  [ksl][row][c]
  __shared__ float vals[4][12];
  __shared__ int   flags[4];
  const int t = threadIdx.x;
  const int b0 = blockIdx.x * 4;
  const int j = t & 255, ks = t >> 8;

  float a[4] = {0.f,0.f,0.f,0.f};
  const float* sb = state + (size_t)b0 * EDIM;
  const int kb = ks * 64;
#pragma unroll 4
  for (int k = kb; k < kb + 64; k += 4) {
    const float w0 = aW1[(k+0)*EDIM + j], w1 = aW1[(k+1)*EDIM + j],
                w2 = aW1[(k+2)*EDIM + j], w3 = aW1[(k+3)*EDIM + j];
#pragma unroll
    for (int i = 0; i < 4; i++) {
      const float4 s4 = *(const float4*)(sb + i * EDIM + k);
      a[i] = fmaf(s4.x, w0, a[i]); a[i] = fmaf(s4.y, w1, a[i]);
      a[i] = fmaf(s4.z, w2, a[i]); a[i] = fmaf(s4.w, w3, a[i]);
    }
  }
  *(float4*)&P[ks][j][0] = make_float4(a[0], a[1], a[2], a[3]);
  __syncthreads();
  {
    const int j2 = t & 255, i = t >> 8;
    float s = P[0][j2][i] + P[1][j2][i] + P[2][j2][i] + P[3][j2][i] + ab1[j2];
    H[j2][i] = fmaxf(s, 0.f);
  }
  __syncthreads();
  {
    const int c = t & 15, i = (t >> 4) & 3, ksl = t >> 6;
    float a2 = 0.f;
    if (c < 12) {
      const int k0 = ksl * 16;
#pragma unroll 4
      for (int k = k0; k < k0 + 16; k++)
        a2 = fmaf(H[k][i], aW2[k * 12 + c], a2);
    }
    P2[ksl][i][c] = a2;
  }
  __syncthreads();
  if (t < 48) {
    const int i = t / 12, c = t % 12;
    float s = 0.f;
#pragma unroll
    for (int w = 0; w < 16; w++) s += P2[w][i][c];
    const float logit = s + ab2[c];
    const uint32_t L = (uint32_t)((b0 + i) * 12 + c);
    const float u = jax_uniform(jax_bits12288(fk0, fk1, L));
    const float g = -logf(-logf(u));
    vals[i][c] = logit + g;   // TAU=1, softmax monotone -> argmax on logits+gumbel
  }
  __syncthreads();
  if (t < 4) {
    const int b = b0 + t;
    int idx0 = 0, idx1 = 0, idx2 = 0;
    { float best = vals[t][0];
#pragma unroll
      for (int c = 1; c < 4; c++) { float v = vals[t][c];     if (v > best) { best = v; idx0 = c; } } }
    { float best = vals[t][4];
#pragma unroll
      for (int c = 1; c < 4; c++) { float v = vals[t][4 + c]; if (v > best) { best = v; idx1 = c; } } }
    { float best = vals[t][8];
#pragma unroll
      for (int c = 1; c < 4; c++) { float v = vals[t][8 + c]; if (v > best) { best = v; idx2 = c; } } }
    const int nn = idx0 * 16 + idx1 * 4 + idx2;
    int nxt;
    if (step == 0)      { exited[b] = 0; nxt = nn; }
    else if (step < 4)  {
      if (exited[b])      nxt = -1;
      else if (nn == 0) { exited[b] = 1; nxt = -1; }
      else                nxt = nn;
    } else                nxt = exited[b] ? 0 : nn;
    n_next[b] = nxt; flags[t] = nxt;
    if (nxt >= 0) atomicAdd(&count[nxt], 1);
  }
  __syncthreads();
  {  // frozen rows: copy state forward into the next buffer (k_blocks skips them)
    const int i = t >> 8, jj = t & 255;
    if (flags[i] < 0) sout[(size_t)(b0 + i) * EDIM + jj] = sb[i * EDIM + jj];
  }
}

// ---------------- routed block eval, CHUNK=4 rows/WG, row list via ballot-scan ----------------
__global__ __launch_bounds__(1024) void k_blocks(
    const float* __restrict__ sin,
    const float* __restrict__ W1, const float* __restrict__ b1,
    const float* __restrict__ W2, const float* __restrict__ b2,
    const int* __restrict__ count, const int* __restrict__ n_next,
    const float* __restrict__ initial, float* __restrict__ sout,
    int* __restrict__ count_next, int is_final) {
  __shared__ float P[8][128][8];    // 32KB partials [ks][jc][co*4+row]
  __shared__ float H[256][4];       // 4KB
  __shared__ int   meta[4];         // n, local, m, total_chunks
  __shared__ int   rowsl[4];
  __shared__ float denom[4];
  __shared__ int   wcnt[16], wbase[16];
  const int t = threadIdx.x, c = blockIdx.x;
  if (c == 0 && t < 64) count_next[t] = 0;   // zero NEXT round's counters
  if (t < 4) rowsl[t] = 0;                   // defensive init (profiling replays)
  if (t < 64) {                              // wave 0: chunk assignment from counts
    const int cnt = count[t];
    const int nch = (cnt + 3) >> 2;
    int icnt = cnt, inch = nch;
#pragma unroll
    for (int d = 1; d < 64; d <<= 1) {
      int t1 = __shfl_up(icnt, d), t2 = __shfl_up(inch, d);
      if (t >= d) { icnt += t1; inch += t2; }
    }
    const int ench = inch - nch;
    const int total = __shfl(inch, 63);
    if (t == 0) meta[3] = total;
    if (c >= ench && c < ench + nch) {
      meta[0] = t; meta[1] = c - ench;
      meta[2] = min(4, cnt - (c - ench) * 4);
    }
  }
  __syncthreads();
  if (c >= meta[3]) return;                  // uniform exit (spare WGs)
  const int n = meta[0], local = meta[1], m = meta[2];

  // ordered row list of block n via ballot-scan of n_next (thread t <-> row t)
  const int nn = n_next[t];
  const bool flag = (nn == n);
  const unsigned long long bal = __ballot(flag);
  const int wid = t >> 6, lane = t & 63;
  if (lane == 0) wcnt[wid] = __popcll(bal);
  __syncthreads();
  if (t == 0) { int s = 0; for (int w = 0; w < 16; w++) { wbase[w] = s; s += wcnt[w]; } }
  __syncthreads();
  if (flag) {
    const int rank = wbase[wid] + __popcll(bal & ((1ull << lane) - 1ull));
    const int r0 = local * 4;
    if (rank >= r0 && rank < r0 + 4) rowsl[rank - r0] = t;
  }
  __syncthreads();

  int rs[4];
#pragma unroll
  for (int i = 0; i < 4; i++) rs[i] = rowsl[min(i, m - 1)] & 1023;

  // ||state_row||: wave i reduces row i
  if (t < 256) {
    const int i = t >> 6, l = t & 63;
    const float4 v = *(const float4*)(sin + (size_t)rs[i] * EDIM + l * 4);
    float sq = v.x*v.x + v.y*v.y + v.z*v.z + v.w*v.w;
#pragma unroll
    for (int d = 32; d >= 1; d >>= 1) sq += __shfl_xor(sq, d);
    if (l == 0) denom[i] = sqrtf(sq) + 1e-6f;
  }

  // layer 1: thread = (jc in [0,128) -> cols jc, jc+128; ks in [0,8) -> K-slice of 32)
  const int jc = t & 127, ks = t >> 7;
  const float* W1n = W1 + (size_t)n * EDIM * EDIM;
  float a0[4] = {0.f,0.f,0.f,0.f}, a1[4] = {0.f,0.f,0.f,0.f};
  const int kb = ks * 32;
#pragma unroll 4
  for (int k = kb; k < kb + 32; k += 4) {
    const float w0A = W1n[(k+0)*EDIM + jc],       w1A = W1n[(k+1)*EDIM + jc],
                w2A = W1n[(k+2)*EDIM + jc],       w3A = W1n[(k+3)*EDIM + jc];
    const float w0B = W1n[(k+0)*EDIM + jc + 128], w1B = W1n[(k+1)*EDIM + jc + 128],
                w2B = W1n[(k+2)*EDIM + jc + 128], w3B = W1n[(k+3)*EDIM + jc + 128];
#pragma unroll
    for (int i = 0; i < 4; i++) {
      const float4 s4 = *(const float4*)(sin + (size_t)rs[i] * EDIM + k);
      a0[i] = fmaf(s4.x, w0A, a0[i]); a0[i] = fmaf(s4.y, w1A, a0[i]);
      a0[i] = fmaf(s4.z, w2A, a0[i]); a0[i] = fmaf(s4.w, w3A, a0[i]);
      a1[i] = fmaf(s4.x, w0B, a1[i]); a1[i] = fmaf(s4.y, w1B, a1[i]);
      a1[i] = fmaf(s4.z, w2B, a1[i]); a1[i] = fmaf(s4.w, w3B, a1[i]);
    }
  }
  { float4* pp = (float4*)&P[ks][jc][0];
    pp[0] = make_float4(a0[0], a0[1], a0[2], a0[3]);
    pp[1] = make_float4(a1[0], a1[1], a1[2], a1[3]); }
  __syncthreads();
  {  // reduce -> H[k][row]
    const int jk = t & 255, i = t >> 8;
    const int jh = jk & 127, co = jk >> 7;
    float s = 0.f;
#pragma unroll
    for (int w = 0; w < 8; w++) s += P[w][jh][co * 4 + i];
    s += b1[(size_t)n * EDIM + jk];
    H[jk][i] = fmaxf(s, 0.f);
  }
  __syncthreads();
  // layer 2: one ds_read_b128 broadcast per k feeds 8 FMA
  const float* W2n = W2 + (size_t)n * EDIM * EDIM;
  float c0[4] = {0.f,0.f,0.f,0.f}, c1[4] = {0.f,0.f,0.f,0.f};
#pragma unroll 4
  for (int k = kb; k < kb + 32; k++) {
    const float4 h4 = *(const float4*)&H[k][0];
    const float wA = W2n[k*EDIM + jc], wB = W2n[k*EDIM + jc + 128];
    c0[0] = fmaf(h4.x, wA, c0[0]); c0[1] = fmaf(h4.y, wA, c0[1]);
    c0[2] = fmaf(h4.z, wA, c0[2]); c0[3] = fmaf(h4.w, wA, c0[3]);
    c1[0] = fmaf(h4.x, wB, c1[0]); c1[1] = fmaf(h4.y, wB, c1[1]);
    c1[2] = fmaf(h4.z, wB, c1[2]); c1[3] = fmaf(h4.w, wB, c1[3]);
  }
  { float4* pp = (float4*)&P[ks][jc][0];   // P reads all consumed before H barrier
    pp[0] = make_float4(c0[0], c0[1], c0[2], c0[3]);
    pp[1] = make_float4(c1[0], c1[1], c1[2], c1[3]); }
  __syncthreads();
  {  // final reduce + relu + /norm (+ initial on final round)
    const int col = t & 255, i = t >> 8;
    if (i < m) {
      const int jh = col & 127, co = col >> 7;
      float s = 0.f;
#pragma unroll
      for (int w = 0; w < 8; w++) s += P[w][jh][co * 4 + i];
      s += b2[(size_t)n * EDIM + col];
      float v = fmaxf(s, 0.f) / denom[i];
      const int row = rowsl[i] & 1023;
      if (is_final) v += initial[(size_t)row * EDIM + col];
      sout[(size_t)row * EDIM + col] = v;
    }
  }
}

// ---------------- output head ----------------
__global__ __launch_bounds__(1024) void k_head(
    const float* __restrict__ fin,
    const float* __restrict__ oW1, const float* __restrict__ ob1,
    const float* __restrict__ oW2, const float* __restrict__ ob2,
    float* __restrict__ out) {
  __shared__ float P[4][256][4];
  __shared__ float H[256][4];
  __shared__ float P2[16][4][16];
  const int t = threadIdx.x;
  const int b0 = blockIdx.x * 4;
  const int j = t & 255, ks = t >> 8;
  float a[4] = {0.f,0.f,0.f,0.f};
  const float* sb = fin + (size_t)b0 * EDIM;
  const int kb = ks * 64;
#pragma unroll 4
  for (int k = kb; k < kb + 64; k += 4) {
    const float w0 = oW1[(k+0)*EDIM + j], w1 = oW1[(k+1)*EDIM + j],
                w2 = oW1[(k+2)*EDIM + j], w3 = oW1[(k+3)*EDIM + j];
#pragma unroll
    for (int i = 0; i < 4; i++) {
      const float4 s4 = *(const float4*)(sb + i * EDIM + k);
      a[i] = fmaf(s4.x, w0, a[i]); a[i] = fmaf(s4.y, w1, a[i]);
      a[i] = fmaf(s4.z, w2, a[i]); a[i] = fmaf(s4.w, w3, a[i]);
    }
  }
  *(float4*)&P[ks][j][0] = make_float4(a[0], a[1], a[2], a[3]);
  __syncthreads();
  {
    const int j2 = t & 255, i = t >> 8;
    float s = P[0][j2][i] + P[1][j2][i] + P[2][j2][i] + P[3][j2][i] + ob1[j2];
    H[j2][i] = fmaxf(s, 0.f);
  }
  __syncthreads();
  {
    const int c = t & 15, i = (t >> 4) & 3, ksl = t >> 6;
    float a2 = 0.f;
    if (c < 10) {
      const int k0 = ksl * 16;
#pragma unroll 4
      for (int k = k0; k < k0 + 16; k++)
        a2 = fmaf(H[k][i], oW2[k * 10 + c], a2);
    }
    P2[ksl][i][c] = a2;
  }
  __syncthreads();
  if (t < 40) {
    const int i = t / 10, c = t % 10;
    float s = 0.f;
#pragma unroll
    for (int w = 0; w < 16; w++) s += P2[w][i][c];
    out[(size_t)(b0 + i) * 10 + c] = s + ob2[c];
  }
}

// ---------------- launch ----------------
extern "C" void kernel_launch(void* const* d_in, const int* in_sizes, int n_in,
                              void* d_out, int out_size, void* d_ws, size_t ws_size,
                              hipStream_t stream) {
  const float* x    = (const float*)d_in[0];
  const float* Wemb = (const float*)d_in[1];
  const float* bemb = (const float*)d_in[2];
  const float* stW1 = (const float*)d_in[3];
  const float* stb1 = (const float*)d_in[4];
  const float* stW2 = (const float*)d_in[5];
  const float* stb2 = (const float*)d_in[6];
  const float* aW1  = (const float*)d_in[7];
  const float* ab1  = (const float*)d_in[8];
  const float* aW2  = (const float*)d_in[9];
  const float* ab2  = (const float*)d_in[10];
  const float* oW1  = (const float*)d_in[11];
  const float* ob1  = (const float*)d_in[12];
  const float* oW2  = (const float*)d_in[13];
  const float* ob2  = (const float*)d_in[14];
  float* out = (float*)d_out;

  char* ws = (char*)d_ws;
  auto alloc = [&](size_t bytes) { char* p = ws; ws += (bytes + 255) & ~(size_t)255; return p; };
  float* stateA  = (float*)alloc((size_t)BATCH * EDIM * 4);
  float* stateB  = (float*)alloc((size_t)BATCH * EDIM * 4);
  float* initial = (float*)alloc((size_t)BATCH * EDIM * 4);
  float* finalb  = (float*)alloc((size_t)BATCH * EDIM * 4);
  int* exited = (int*)alloc(BATCH * 4);
  int* n_next = (int*)alloc(BATCH * 4);
  int* counters[2];
  counters[0] = (int*)alloc(64 * 4);
  counters[1] = (int*)alloc(64 * 4);

  // fold_in(key(42), s) on host: threefry(k=[0,42], x=[0,s])
  uint32_t fk0[5], fk1[5];
  for (uint32_t s = 0; s < 5; s++) threefry2x32(0u, 42u, 0u, s, &fk0[s], &fk1[s]);

  k_embed<<<BATCH / 8, 1024, 0, stream>>>(x, Wemb, bemb, stateA, initial, counters[0]);

  float* cur = stateA;
  float* nxt = stateB;
  for (int j = 0; j < 5; j++) {
    int* cnt  = counters[j & 1];
    int* cntN = counters[(j + 1) & 1];
    float* dst = (j < 4) ? nxt : finalb;
    k_addr<<<BATCH / 4, 1024, 0, stream>>>(cur, aW1, ab1, aW2, ab2,
        exited, n_next, cnt, dst, j, fk0[j], fk1[j]);
    k_blocks<<<GRID_BE, 1024, 0, stream>>>(cur, stW1, stb1, stW2, stb2,
        cnt, n_next, initial, dst, cntN, (j == 4) ? 1 : 0);
    if (j < 4) { float* tmp = cur; cur = nxt; nxt = tmp; }
  }
  k_head<<<BATCH / 4, 1024, 0, stream>>>(finalb, oW1, ob1, oW2, ob2, out);
}

// Round 3
// 265.924 us; speedup vs baseline: 2.9901x; 1.5763x over previous
//
#include <hip/hip_runtime.h>
#include <stdint.h>

// SelfOrganizingBrain: B=1024, IN=784, E=256, NCLS=10, N=64 blocks, NJUMPS=4.
// R2: LDS-stage activation rows in every GEMM kernel (kill L1 thrash from
// streaming weights), fill all 256 CUs (embed col-split), CHUNK=8 blocks,
// stride-9/12 LDS padding for conflict-free partial reduce.
// 12 dispatches: embed + 5x(addr, blocks) + head. All fp32 (argmax-critical).

#define BATCH 1024
#define EDIM  256
#define INDIM 784
#define GRID_BE 192   // max chunks = 64 + (1024-64)/8 = 184 <= 192

// ---------------- threefry2x32 (exact JAX semantics, validated R0/R1) ----------------
__host__ __device__ inline uint32_t rotl32(uint32_t x, uint32_t d) {
  return (x << d) | (x >> (32u - d));
}
__host__ __device__ inline void threefry2x32(uint32_t k0, uint32_t k1,
                                             uint32_t x0, uint32_t x1,
                                             uint32_t* o0, uint32_t* o1) {
  uint32_t ks2 = k0 ^ k1 ^ 0x1BD11BDAu;
  x0 += k0; x1 += k1;
#define TF_R(a) { x0 += x1; x1 = rotl32(x1, a); x1 ^= x0; }
  TF_R(13) TF_R(15) TF_R(26) TF_R(6)   x0 += k1;  x1 += ks2 + 1u;
  TF_R(17) TF_R(29) TF_R(16) TF_R(24)  x0 += ks2; x1 += k0  + 2u;
  TF_R(13) TF_R(15) TF_R(26) TF_R(6)   x0 += k0;  x1 += k1  + 3u;
  TF_R(17) TF_R(29) TF_R(16) TF_R(24)  x0 += k1;  x1 += ks2 + 4u;
  TF_R(13) TF_R(15) TF_R(26) TF_R(6)   x0 += ks2; x1 += k0  + 5u;
#undef TF_R
  *o0 = x0; *o1 = x1;
}
__device__ inline uint32_t jax_bits12288(uint32_t k0, uint32_t k1, uint32_t L) {
  uint32_t o0, o1;
  if (L < 6144u) { threefry2x32(k0, k1, L, L + 6144u, &o0, &o1); return o0; }
  else           { threefry2x32(k0, k1, L - 6144u, L, &o0, &o1); return o1; }
}
__device__ inline float jax_uniform(uint32_t bits) {
  const float minv = 1e-6f;
  const float maxv = (float)(1.0 - 1e-06);
  const float span = maxv - minv;
  uint32_t fb = (bits >> 9) | 0x3f800000u;
  float f = __uint_as_float(fb) - 1.0f;
  float u = __fadd_rn(__fmul_rn(f, span), minv);
  return fmaxf(minv, u);
}

// ---------------- embed: grid 256 = (rg 128 x colhalf 2), block 1024 = (jl 128, ks 8) ----------------
__global__ __launch_bounds__(1024) void k_embed(
    const float* __restrict__ x, const float* __restrict__ Wemb,
    const float* __restrict__ bemb,
    float* __restrict__ stateA, float* __restrict__ initial,
    int* __restrict__ count0) {
  __shared__ float XS[8 * INDIM];      // 25KB: 8 rows of x
  __shared__ float P[8][128][9];       // 36.9KB: partials, stride-9 (conflict-free reduce)
  const int t = threadIdx.x;
  if (blockIdx.x == 0 && t < 64) count0[t] = 0;
  const int rg = blockIdx.x >> 1, ch = blockIdx.x & 1;
  const int jl = t & 127, ks = t >> 7;

  // stage 8 x-rows (coalesced float4): 1568 float4
  {
    const float4* src = (const float4*)(x + (size_t)rg * 8 * INDIM);
    float4* dst = (float4*)XS;
    for (int p = t; p < (8 * INDIM) / 4; p += 1024) dst[p] = src[p];
  }
  __syncthreads();

  const int col = ch * 128 + jl;
  const int kb = (ks < 4) ? ks * 100 : 400 + (ks - 4) * 96;
  const int ke = kb + ((ks < 4) ? 100 : 96);
  float a[8] = {0.f,0.f,0.f,0.f,0.f,0.f,0.f,0.f};
#pragma unroll 2
  for (int k = kb; k < ke; k += 4) {
    const float w0 = Wemb[(k+0)*EDIM + col], w1 = Wemb[(k+1)*EDIM + col],
                w2 = Wemb[(k+2)*EDIM + col], w3 = Wemb[(k+3)*EDIM + col];
#pragma unroll
    for (int i = 0; i < 8; i++) {
      const float4 s4 = *(const float4*)&XS[i * INDIM + k];   // LDS broadcast
      a[i] = fmaf(s4.x, w0, a[i]); a[i] = fmaf(s4.y, w1, a[i]);
      a[i] = fmaf(s4.z, w2, a[i]); a[i] = fmaf(s4.w, w3, a[i]);
    }
  }
#pragma unroll
  for (int q = 0; q < 8; q++) P[ks][jl][q] = a[q];
  __syncthreads();
  {
    const int c2 = t & 127, i = t >> 7;
    float s = 0.f;
#pragma unroll
    for (int w = 0; w < 8; w++) s += P[w][c2][i];
    s += bemb[ch * 128 + c2];
    const size_t idx = (size_t)(rg * 8 + i) * EDIM + ch * 128 + c2;
    stateA[idx] = s; initial[idx] = s;
  }
}

// ---------------- addr MLP + gumbel argmax + bookkeeping + frozen-copy ----------------
// grid 256 (4 rows/WG), block 1024 = (j 256, ks 4), K-slice 64. State staged in LDS.
__global__ __launch_bounds__(1024) void k_addr(
    const float* __restrict__ state,
    const float* __restrict__ aW1, const float* __restrict__ ab1,
    const float* __restrict__ aW2, const float* __restrict__ ab2,
    int* __restrict__ exited, int* __restrict__ n_next, int* __restrict__ count,
    float* __restrict__ sout, int step, uint32_t fk0, uint32_t fk1) {
  __shared__ float XS[4 * EDIM];       // 4KB
  __shared__ float P[4][256][5];       // 20KB stride-5
  __shared__ float H[EDIM][4];         // 4KB
  __shared__ float P2[16][4][16];      // 4KB
  __shared__ float vals[4][12];
  __shared__ int   flags[4];
  const int t = threadIdx.x, b0 = blockIdx.x * 4;

  XS[t] = state[(size_t)b0 * EDIM + t];   // 4 rows, coalesced
  __syncthreads();

  const int j = t & 255, ks = t >> 8;
  const int kb = ks * 64;
  float a[4] = {0.f,0.f,0.f,0.f};
#pragma unroll 2
  for (int k = kb; k < kb + 64; k += 4) {
    const float w0 = aW1[(k+0)*EDIM + j], w1 = aW1[(k+1)*EDIM + j],
                w2 = aW1[(k+2)*EDIM + j], w3 = aW1[(k+3)*EDIM + j];
#pragma unroll
    for (int i = 0; i < 4; i++) {
      const float4 s4 = *(const float4*)&XS[i * EDIM + k];
      a[i] = fmaf(s4.x, w0, a[i]); a[i] = fmaf(s4.y, w1, a[i]);
      a[i] = fmaf(s4.z, w2, a[i]); a[i] = fmaf(s4.w, w3, a[i]);
    }
  }
#pragma unroll
  for (int q = 0; q < 4; q++) P[ks][j][q] = a[q];
  __syncthreads();
  {
    const int j2 = t & 255, i = t >> 8;
    float s = P[0][j2][i] + P[1][j2][i] + P[2][j2][i] + P[3][j2][i] + ab1[j2];
    H[j2][i] = fmaxf(s, 0.f);
  }
  __syncthreads();
  {
    const int c = t & 15, i = (t >> 4) & 3, ksl = t >> 6;
    float a2 = 0.f;
    if (c < 12) {
      const int k0 = ksl * 16;
#pragma unroll 4
      for (int k = k0; k < k0 + 16; k++)
        a2 = fmaf(H[k][i], aW2[k * 12 + c], a2);
    }
    P2[ksl][i][c] = a2;
  }
  __syncthreads();
  if (t < 48) {
    const int i = t / 12, c = t % 12;
    float s = 0.f;
#pragma unroll
    for (int w = 0; w < 16; w++) s += P2[w][i][c];
    const float logit = s + ab2[c];
    const uint32_t L = (uint32_t)((b0 + i) * 12 + c);
    const float u = jax_uniform(jax_bits12288(fk0, fk1, L));
    const float g = -logf(-logf(u));
    vals[i][c] = logit + g;            // TAU=1, softmax monotone -> argmax
  }
  __syncthreads();
  if (t < 4) {
    const int b = b0 + t;
    int idx0 = 0, idx1 = 0, idx2 = 0;
    { float best = vals[t][0];
#pragma unroll
      for (int c = 1; c < 4; c++) { float v = vals[t][c];     if (v > best) { best = v; idx0 = c; } } }
    { float best = vals[t][4];
#pragma unroll
      for (int c = 1; c < 4; c++) { float v = vals[t][4 + c]; if (v > best) { best = v; idx1 = c; } } }
    { float best = vals[t][8];
#pragma unroll
      for (int c = 1; c < 4; c++) { float v = vals[t][8 + c]; if (v > best) { best = v; idx2 = c; } } }
    const int nn = idx0 * 16 + idx1 * 4 + idx2;
    int nxt;
    if (step == 0)      { exited[b] = 0; nxt = nn; }
    else if (step < 4)  {
      if (exited[b])      nxt = -1;
      else if (nn == 0) { exited[b] = 1; nxt = -1; }
      else                nxt = nn;
    } else                nxt = exited[b] ? 0 : nn;
    n_next[b] = nxt; flags[t] = nxt;
    if (nxt >= 0) atomicAdd(&count[nxt], 1);
  }
  __syncthreads();
  {  // frozen rows: copy state forward from LDS
    const int i = t >> 8, jj = t & 255;
    if (flags[i] < 0) sout[(size_t)(b0 + i) * EDIM + jj] = XS[i * EDIM + jj];
  }
}

// ---------------- routed block eval, CHUNK=8 rows/WG, rows staged in LDS ----------------
__global__ __launch_bounds__(1024) void k_blocks(
    const float* __restrict__ sin,
    const float* __restrict__ W1, const float* __restrict__ b1,
    const float* __restrict__ W2, const float* __restrict__ b2,
    const int* __restrict__ count, const int* __restrict__ n_next,
    const float* __restrict__ initial, float* __restrict__ sout,
    int* __restrict__ count_next, int is_final) {
  __shared__ float XS[8 * EDIM];       // 8KB row stage
  __shared__ float P[4][256][9];       // 36.9KB stride-9 partials (both layers)
  __shared__ float H[EDIM][12];        // 12KB stride-12 (16B-aligned b128 broadcast)
  __shared__ int   meta[4];
  __shared__ int   rowsl[8];
  __shared__ float denom[8];
  __shared__ int   wcnt[16], wbase[16];
  const int t = threadIdx.x, c = blockIdx.x;
  if (c == 0 && t < 64) count_next[t] = 0;
  if (t < 8) rowsl[t] = 0;
  if (t < 64) {                        // chunk assignment from counts (CHUNK=8)
    const int cnt = count[t];
    const int nch = (cnt + 7) >> 3;
    int icnt = cnt, inch = nch;
#pragma unroll
    for (int d = 1; d < 64; d <<= 1) {
      int t1 = __shfl_up(icnt, d), t2 = __shfl_up(inch, d);
      if (t >= d) { icnt += t1; inch += t2; }
    }
    const int ench = inch - nch;
    const int total = __shfl(inch, 63);
    if (t == 0) meta[3] = total;
    if (c >= ench && c < ench + nch) {
      meta[0] = t; meta[1] = c - ench;
      meta[2] = min(8, cnt - (c - ench) * 8);
    }
  }
  __syncthreads();
  if (c >= meta[3]) return;
  const int n = meta[0], local = meta[1], m = meta[2];

  // ordered row list via ballot-scan of n_next (thread t <-> row t)
  {
    const bool flag = (n_next[t] == n);
    const unsigned long long bal = __ballot(flag);
    const int wid = t >> 6, lane = t & 63;
    if (lane == 0) wcnt[wid] = __popcll(bal);
    __syncthreads();
    if (t == 0) { int s = 0; for (int w = 0; w < 16; w++) { wbase[w] = s; s += wcnt[w]; } }
    __syncthreads();
    if (flag) {
      const int rank = wbase[wid] + __popcll(bal & ((1ull << lane) - 1ull));
      const int r0 = local * 8;
      if (rank >= r0 && rank < r0 + 8) rowsl[rank - r0] = t;
    }
    __syncthreads();
  }

  // stage 8 rows into LDS (coalesced float4) + norms
  if (t < 512) {
    const int i = t >> 6, q = t & 63;
    const int row = rowsl[min(i, m - 1)] & 1023;
    const float4 v = *(const float4*)(sin + (size_t)row * EDIM + q * 4);
    ((float4*)XS)[t] = v;
    float sq = v.x*v.x + v.y*v.y + v.z*v.z + v.w*v.w;
#pragma unroll
    for (int d = 32; d >= 1; d >>= 1) sq += __shfl_xor(sq, d);
    if (q == 0) denom[i] = sqrtf(sq) + 1e-6f;
  }
  __syncthreads();

  // layer 1: (j 256, ks 4), K-slice 64
  const int j = t & 255, ks = t >> 8;
  const int kb = ks * 64;
  const float* W1n = W1 + (size_t)n * EDIM * EDIM;
  {
    float a[8] = {0.f,0.f,0.f,0.f,0.f,0.f,0.f,0.f};
#pragma unroll 2
    for (int k = kb; k < kb + 64; k += 4) {
      const float w0 = W1n[(k+0)*EDIM + j], w1 = W1n[(k+1)*EDIM + j],
                  w2 = W1n[(k+2)*EDIM + j], w3 = W1n[(k+3)*EDIM + j];
#pragma unroll
      for (int i = 0; i < 8; i++) {
        const float4 s4 = *(const float4*)&XS[i * EDIM + k];
        a[i] = fmaf(s4.x, w0, a[i]); a[i] = fmaf(s4.y, w1, a[i]);
        a[i] = fmaf(s4.z, w2, a[i]); a[i] = fmaf(s4.w, w3, a[i]);
      }
    }
#pragma unroll
    for (int q = 0; q < 8; q++) P[ks][j][q] = a[q];
  }
  __syncthreads();
  {  // H reduce: 2 outputs/thread
    const int j2 = t & 255, ih = t >> 8;
    const float bb = b1[(size_t)n * EDIM + j2];
#pragma unroll
    for (int qq = 0; qq < 2; qq++) {
      const int i = ih + qq * 4;
      float s = P[0][j2][i] + P[1][j2][i] + P[2][j2][i] + P[3][j2][i] + bb;
      H[j2][i] = fmaxf(s, 0.f);
    }
  }
  __syncthreads();
  // layer 2: per k: 1 w load + 2 LDS b128 broadcasts + 8 FMA
  const float* W2n = W2 + (size_t)n * EDIM * EDIM;
  {
    float a[8] = {0.f,0.f,0.f,0.f,0.f,0.f,0.f,0.f};
#pragma unroll 4
    for (int k = kb; k < kb + 64; k++) {
      const float w = W2n[k*EDIM + j];
      const float4 h0 = *(const float4*)&H[k][0];
      const float4 h1 = *(const float4*)&H[k][4];
      a[0] = fmaf(h0.x, w, a[0]); a[1] = fmaf(h0.y, w, a[1]);
      a[2] = fmaf(h0.z, w, a[2]); a[3] = fmaf(h0.w, w, a[3]);
      a[4] = fmaf(h1.x, w, a[4]); a[5] = fmaf(h1.y, w, a[5]);
      a[6] = fmaf(h1.z, w, a[6]); a[7] = fmaf(h1.w, w, a[7]);
    }
#pragma unroll
    for (int q = 0; q < 8; q++) P[ks][j][q] = a[q];
  }
  __syncthreads();
  {  // final reduce + relu + /norm (+ initial on final round)
    const int col = t & 255, ih = t >> 8;
    const float bb2 = b2[(size_t)n * EDIM + col];
#pragma unroll
    for (int qq = 0; qq < 2; qq++) {
      const int i = ih + qq * 4;
      if (i < m) {
        float s = P[0][col][i] + P[1][col][i] + P[2][col][i] + P[3][col][i] + bb2;
        float v = fmaxf(s, 0.f) / denom[i];
        const int row = rowsl[i] & 1023;
        if (is_final) v += initial[(size_t)row * EDIM + col];
        sout[(size_t)row * EDIM + col] = v;
      }
    }
  }
}

// ---------------- output head: grid 256 (4 rows/WG) ----------------
__global__ __launch_bounds__(1024) void k_head(
    const float* __restrict__ fin,
    const float* __restrict__ oW1, const float* __restrict__ ob1,
    const float* __restrict__ oW2, const float* __restrict__ ob2,
    float* __restrict__ out) {
  __shared__ float XS[4 * EDIM];
  __shared__ float P[4][256][5];
  __shared__ float H[EDIM][4];
  __shared__ float P2[16][4][16];
  const int t = threadIdx.x, b0 = blockIdx.x * 4;
  XS[t] = fin[(size_t)b0 * EDIM + t];
  __syncthreads();
  const int j = t & 255, ks = t >> 8;
  const int kb = ks * 64;
  float a[4] = {0.f,0.f,0.f,0.f};
#pragma unroll 2
  for (int k = kb; k < kb + 64; k += 4) {
    const float w0 = oW1[(k+0)*EDIM + j], w1 = oW1[(k+1)*EDIM + j],
                w2 = oW1[(k+2)*EDIM + j], w3 = oW1[(k+3)*EDIM + j];
#pragma unroll
    for (int i = 0; i < 4; i++) {
      const float4 s4 = *(const float4*)&XS[i * EDIM + k];
      a[i] = fmaf(s4.x, w0, a[i]); a[i] = fmaf(s4.y, w1, a[i]);
      a[i] = fmaf(s4.z, w2, a[i]); a[i] = fmaf(s4.w, w3, a[i]);
    }
  }
#pragma unroll
  for (int q = 0; q < 4; q++) P[ks][j][q] = a[q];
  __syncthreads();
  {
    const int j2 = t & 255, i = t >> 8;
    float s = P[0][j2][i] + P[1][j2][i] + P[2][j2][i] + P[3][j2][i] + ob1[j2];
    H[j2][i] = fmaxf(s, 0.f);
  }
  __syncthreads();
  {
    const int c = t & 15, i = (t >> 4) & 3, ksl = t >> 6;
    float a2 = 0.f;
    if (c < 10) {
      const int k0 = ksl * 16;
#pragma unroll 4
      for (int k = k0; k < k0 + 16; k++)
        a2 = fmaf(H[k][i], oW2[k * 10 + c], a2);
    }
    P2[ksl][i][c] = a2;
  }
  __syncthreads();
  if (t < 40) {
    const int i = t / 10, c = t % 10;
    float s = 0.f;
#pragma unroll
    for (int w = 0; w < 16; w++) s += P2[w][i][c];
    out[(size_t)(b0 + i) * 10 + c] = s + ob2[c];
  }
}

// ---------------- launch ----------------
extern "C" void kernel_launch(void* const* d_in, const int* in_sizes, int n_in,
                              void* d_out, int out_size, void* d_ws, size_t ws_size,
                              hipStream_t stream) {
  const float* x    = (const float*)d_in[0];
  const float* Wemb = (const float*)d_in[1];
  const float* bemb = (const float*)d_in[2];
  const float* stW1 = (const float*)d_in[3];
  const float* stb1 = (const float*)d_in[4];
  const float* stW2 = (const float*)d_in[5];
  const float* stb2 = (const float*)d_in[6];
  const float* aW1  = (const float*)d_in[7];
  const float* ab1  = (const float*)d_in[8];
  const float* aW2  = (const float*)d_in[9];
  const float* ab2  = (const float*)d_in[10];
  const float* oW1  = (const float*)d_in[11];
  const float* ob1  = (const float*)d_in[12];
  const float* oW2  = (const float*)d_in[13];
  const float* ob2  = (const float*)d_in[14];
  float* out = (float*)d_out;

  char* ws = (char*)d_ws;
  auto alloc = [&](size_t bytes) { char* p = ws; ws += (bytes + 255) & ~(size_t)255; return p; };
  float* stateA  = (float*)alloc((size_t)BATCH * EDIM * 4);
  float* stateB  = (float*)alloc((size_t)BATCH * EDIM * 4);
  float* initial = (float*)alloc((size_t)BATCH * EDIM * 4);
  float* finalb  = (float*)alloc((size_t)BATCH * EDIM * 4);
  int* exited = (int*)alloc(BATCH * 4);
  int* n_next = (int*)alloc(BATCH * 4);
  int* counters[2];
  counters[0] = (int*)alloc(64 * 4);
  counters[1] = (int*)alloc(64 * 4);

  // fold_in(key(42), s) on host: threefry(k=[0,42], x=[0,s])
  uint32_t fk0[5], fk1[5];
  for (uint32_t s = 0; s < 5; s++) threefry2x32(0u, 42u, 0u, s, &fk0[s], &fk1[s]);

  k_embed<<<256, 1024, 0, stream>>>(x, Wemb, bemb, stateA, initial, counters[0]);

  float* cur = stateA;
  float* nxt = stateB;
  for (int j = 0; j < 5; j++) {
    int* cnt  = counters[j & 1];
    int* cntN = counters[(j + 1) & 1];
    float* dst = (j < 4) ? nxt : finalb;
    k_addr<<<BATCH / 4, 1024, 0, stream>>>(cur, aW1, ab1, aW2, ab2,
        exited, n_next, cnt, dst, j, fk0[j], fk1[j]);
    k_blocks<<<GRID_BE, 1024, 0, stream>>>(cur, stW1, stb1, stW2, stb2,
        cnt, n_next, initial, dst, cntN, (j == 4) ? 1 : 0);
    if (j < 4) { float* tmp = cur; cur = nxt; nxt = tmp; }
  }
  k_head<<<BATCH / 4, 1024, 0, stream>>>(finalb, oW1, ob1, oW2, ob2, out);
}